// Round 6
// baseline (2399.766 us; speedup 1.0000x reference)
//
#include <hip/hip_runtime.h>

#define NN 100000
#define NE 3200000
#define DD 256
#define KC 4
#define MPAD 100096  // 782 * 128
#define NBUK ((NN + 255) >> 8)  // 391 buckets of 256 rows
#define INV15 (1.0f / 32767.0f)

typedef _Float16 f16x8 __attribute__((ext_vector_type(8)));
typedef float f32x4 __attribute__((ext_vector_type(4)));

// ---------------------------------------------------------------- CSR build

__global__ __launch_bounds__(256) void k_hist(const int* __restrict__ row,
                                              int* __restrict__ counts) {
    int e = blockIdx.x * 256 + threadIdx.x;
    if (e < NE) atomicAdd(&counts[row[e]], 1);
}

__global__ __launch_bounds__(256) void k_scan1(const int* __restrict__ counts,
                                               int* __restrict__ offs,
                                               int* __restrict__ bsum) {
    __shared__ int s[256];
    const int t = threadIdx.x;
    const int base = blockIdx.x * 1024 + t * 4;
    int v[4];
    int sum = 0;
#pragma unroll
    for (int i = 0; i < 4; ++i) {
        v[i] = (base + i < NN) ? counts[base + i] : 0;
        sum += v[i];
    }
    s[t] = sum;
    __syncthreads();
    for (int off = 1; off < 256; off <<= 1) {
        int x = (t >= off) ? s[t - off] : 0;
        __syncthreads();
        s[t] += x;
        __syncthreads();
    }
    int run = (t > 0) ? s[t - 1] : 0;
#pragma unroll
    for (int i = 0; i < 4; ++i) {
        if (base + i < NN) offs[base + i] = run;
        run += v[i];
    }
    if (t == 255) bsum[blockIdx.x] = s[255];
}

__global__ void k_scan2(int* __restrict__ bsum, int nb) {
    if (threadIdx.x == 0 && blockIdx.x == 0) {
        int run = 0;
        for (int i = 0; i < nb; ++i) {
            int c = bsum[i];
            bsum[i] = run;
            run += c;
        }
    }
}

__global__ __launch_bounds__(256) void k_scan3(int* __restrict__ offs,
                                               const int* __restrict__ bsum) {
    int i = blockIdx.x * 256 + threadIdx.x;
    if (i < NN)
        offs[i] += bsum[i >> 10];
    else if (i == NN)
        offs[NN] = NE;
}

// bucket cursors start at each bucket's base offset
__global__ __launch_bounds__(256) void k_initb(const int* __restrict__ offs,
                                               int* __restrict__ bcur) {
    int b = blockIdx.x * 256 + threadIdx.x;
    if (b < NBUK) bcur[b] = offs[min(b << 8, NN)];
}

// pass 1: bin edges into 391 bucket windows (8B records, sequential bump per bucket)
__global__ __launch_bounds__(256) void k_bin(const int* __restrict__ row,
                                             const int* __restrict__ col,
                                             const float* __restrict__ val,
                                             int* __restrict__ bcur,
                                             int2* __restrict__ recs) {
    int e = blockIdx.x * 256 + threadIdx.x;
    if (e >= NE) return;
    int r = row[e];
    unsigned v15 = (unsigned)(val[e] * 32767.f + 0.5f);
    unsigned packed = (v15 << 17) | (unsigned)col[e];
    int p = atomicAdd(&bcur[r >> 8], 1);
    int2 rec;
    rec.x = (int)packed;
    rec.y = r;
    recs[p] = rec;
}

// pass 2: one workgroup per bucket; place records into exact row slots.
// All scatter writes land in this bucket's ~32KB window -> single-CU locality.
__global__ __launch_bounds__(256) void k_place(const int2* __restrict__ recs,
                                               const int* __restrict__ offs,
                                               int* __restrict__ cur,
                                               unsigned* __restrict__ edges) {
    const int b = blockIdx.x;
    const int lo = b << 8;
    const int hi = min(lo + 256, NN);
    const int base = offs[lo];
    const int end = offs[hi];
    for (int i = base + threadIdx.x; i < end; i += 256) {
        const int2 rec = recs[i];
        const int r = rec.y;
        const int p = offs[r] + atomicAdd(&cur[r], 1);
        edges[p] = (unsigned)rec.x;
    }
}

// ---------------------------------------------------------------- fp16 converts

__global__ __launch_bounds__(256) void k_cvtX(const float* __restrict__ in,
                                              _Float16* __restrict__ out) {
    const size_t base = ((size_t)blockIdx.x * 256 + threadIdx.x) * 8;
    if (base >= (size_t)NN * DD) return;
    f32x4 v0 = __builtin_nontemporal_load(reinterpret_cast<const f32x4*>(in + base));
    f32x4 v1 = __builtin_nontemporal_load(reinterpret_cast<const f32x4*>(in + base + 4));
    f16x8 o;
    o[0] = (_Float16)v0[0]; o[1] = (_Float16)v0[1]; o[2] = (_Float16)v0[2]; o[3] = (_Float16)v0[3];
    o[4] = (_Float16)v1[0]; o[5] = (_Float16)v1[1]; o[6] = (_Float16)v1[2]; o[7] = (_Float16)v1[3];
    *reinterpret_cast<f16x8*>(out + base) = o;
}

__global__ __launch_bounds__(256) void k_cvtW(const float* __restrict__ W1,
                                              const float* __restrict__ W2,
                                              const float* __restrict__ W3,
                                              const float* __restrict__ W4,
                                              _Float16* __restrict__ Wt) {
    __shared__ float s[32][33];
    const float* W = (blockIdx.z == 0) ? W1 : (blockIdx.z == 1) ? W2 : (blockIdx.z == 2) ? W3 : W4;
    _Float16* o = Wt + (size_t)blockIdx.z * DD * DD;
    const int bk = blockIdx.x * 32;
    const int bn = blockIdx.y * 32;
    const int tx = threadIdx.x & 31, ty = threadIdx.x >> 5;
    for (int r = ty; r < 32; r += 8) s[r][tx] = W[(size_t)(bk + r) * DD + bn + tx];
    __syncthreads();
    for (int r = ty; r < 32; r += 8) o[(size_t)(bn + r) * DD + bk + tx] = (_Float16)s[tx][r];
}

// ---------------------------------------------------------------- GEMM fp16 MFMA

__device__ __forceinline__ void load_lds16(const void* g, void* l) {
    __builtin_amdgcn_global_load_lds((const __attribute__((address_space(1))) void*)g,
                                     (__attribute__((address_space(3))) void*)l, 16, 0, 0);
}

__global__ __launch_bounds__(512, 4) void k_gemm_h(const _Float16* __restrict__ X,
                                                   const _Float16* __restrict__ Wt,
                                                   _Float16* __restrict__ Y) {
    __shared__ __align__(16) char lds[49152];  // A[2][8192] | B[2][16384]
    char* const Albase = lds;
    char* const Blbase = lds + 16384;

    const int tid = threadIdx.x;
    const int lane = tid & 63;
    const int wid = tid >> 6;
    const int wr = wid >> 2;
    const int wc = wid & 3;
    const int bm = blockIdx.x * 128;

    const int aoffl = wid * 1024 + lane * 16;
    const int arw = aoffl >> 6;
    const int acb = (aoffl & 63) ^ (((arw >> 1) & 3) << 4);
    const char* const Asrc0 = (const char*)X + ((size_t)(bm + arw) * DD) * 2 + acb;
    char* const Adst0 = Albase + wid * 1024;

    const int boffl0 = wid * 1024 + lane * 16;
    const int brw0 = boffl0 >> 6;
    const int bcb0 = (boffl0 & 63) ^ (((brw0 >> 1) & 3) << 4);
    const char* const Bsrc0 = (const char*)Wt + ((size_t)brw0 * DD) * 2 + bcb0;
    const int boffl1 = 8192 + wid * 1024 + lane * 16;
    const int brw1 = boffl1 >> 6;
    const int bcb1 = (boffl1 & 63) ^ (((brw1 >> 1) & 3) << 4);
    const char* const Bsrc1 = (const char*)Wt + ((size_t)brw1 * DD) * 2 + bcb1;
    char* const Bdst0 = Blbase + wid * 1024;
    char* const Bdst1 = Blbase + 8192 + wid * 1024;

    int aro[4], bro[4];
#pragma unroll
    for (int m = 0; m < 4; ++m) {
        const int r = wr * 64 + m * 16 + (lane & 15);
        aro[m] = r * 64 + ((((lane >> 4) * 16)) ^ (((r >> 1) & 3) << 4));
    }
#pragma unroll
    for (int n = 0; n < 4; ++n) {
        const int r = wc * 64 + n * 16 + (lane & 15);
        bro[n] = r * 64 + ((((lane >> 4) * 16)) ^ (((r >> 1) & 3) << 4));
    }

    f32x4 acc[4][4];
#pragma unroll
    for (int m = 0; m < 4; ++m)
#pragma unroll
        for (int n = 0; n < 4; ++n) acc[m][n] = (f32x4){0.f, 0.f, 0.f, 0.f};

    load_lds16(Asrc0, Adst0);
    load_lds16(Bsrc0, Bdst0);
    load_lds16(Bsrc1, Bdst1);
    __syncthreads();

    for (int kt = 0; kt < 8; ++kt) {
        const int cur = kt & 1;
        if (kt < 7) {
            const size_t kb = (size_t)(kt + 1) * 32 * 2;
            load_lds16(Asrc0 + kb, Adst0 + (cur ^ 1) * 8192);
            load_lds16(Bsrc0 + kb, Bdst0 + (cur ^ 1) * 16384);
            load_lds16(Bsrc1 + kb, Bdst1 + (cur ^ 1) * 16384);
        }
        const char* Ab = Albase + cur * 8192;
        const char* Bb = Blbase + cur * 16384;
        f16x8 af[4], bf[4];
#pragma unroll
        for (int m = 0; m < 4; ++m) af[m] = *reinterpret_cast<const f16x8*>(Ab + aro[m]);
#pragma unroll
        for (int n = 0; n < 4; ++n) bf[n] = *reinterpret_cast<const f16x8*>(Bb + bro[n]);
#pragma unroll
        for (int m = 0; m < 4; ++m)
#pragma unroll
            for (int n = 0; n < 4; ++n)
                acc[m][n] = __builtin_amdgcn_mfma_f32_16x16x32_f16(af[m], bf[n], acc[m][n], 0, 0, 0);
        __syncthreads();
    }

#pragma unroll
    for (int m = 0; m < 4; ++m) {
        const int row = bm + wr * 64 + m * 16 + (lane >> 4) * 4;
#pragma unroll
        for (int n = 0; n < 4; ++n) {
            const int col = wc * 64 + n * 16 + (lane & 15);
#pragma unroll
            for (int j = 0; j < 4; ++j)
                Y[(size_t)(row + j) * DD + col] = (_Float16)acc[m][n][j];
        }
    }
}

// ---------------------------------------------------------------- SpMM fp16 (full D)
// Two 32-lane halves per wave process alternate edges; lane covers 8 dims (16B).

__global__ __launch_bounds__(256) void k_spmm_h(const int* __restrict__ offs,
                                                const unsigned* __restrict__ edges,
                                                const _Float16* __restrict__ Y,
                                                const float* __restrict__ blend,
                                                _Float16* __restrict__ Xout) {
    const int row = blockIdx.x * 4 + (threadIdx.x >> 6);
    if (row >= NN) return;
    const int lane = threadIdx.x & 63;
    const int half = lane >> 5;
    const int sub = lane & 31;
    const int e0 = offs[row], e1 = offs[row + 1];
    float acc[8] = {};
    int e = e0 + half;
    for (; e + 6 < e1; e += 8) {
        const unsigned u0 = edges[e], u1 = edges[e + 2], u2 = edges[e + 4], u3 = edges[e + 6];
        const float v0 = (float)(u0 >> 17) * INV15;
        const float v1 = (float)(u1 >> 17) * INV15;
        const float v2 = (float)(u2 >> 17) * INV15;
        const float v3 = (float)(u3 >> 17) * INV15;
        const f16x8 y0 = *reinterpret_cast<const f16x8*>(Y + ((size_t)(u0 & 0x1FFFFu) << 8) + sub * 8);
        const f16x8 y1 = *reinterpret_cast<const f16x8*>(Y + ((size_t)(u1 & 0x1FFFFu) << 8) + sub * 8);
        const f16x8 y2 = *reinterpret_cast<const f16x8*>(Y + ((size_t)(u2 & 0x1FFFFu) << 8) + sub * 8);
        const f16x8 y3 = *reinterpret_cast<const f16x8*>(Y + ((size_t)(u3 & 0x1FFFFu) << 8) + sub * 8);
#pragma unroll
        for (int j = 0; j < 8; ++j)
            acc[j] += v0 * (float)y0[j] + v1 * (float)y1[j] + v2 * (float)y2[j] + v3 * (float)y3[j];
    }
    for (; e < e1; e += 2) {
        const unsigned u = edges[e];
        const float v = (float)(u >> 17) * INV15;
        const f16x8 y = *reinterpret_cast<const f16x8*>(Y + ((size_t)(u & 0x1FFFFu) << 8) + sub * 8);
#pragma unroll
        for (int j = 0; j < 8; ++j) acc[j] += v * (float)y[j];
    }
#pragma unroll
    for (int j = 0; j < 8; ++j) acc[j] += __shfl_xor(acc[j], 32);
    if (half == 0) {
        const size_t bi = (size_t)row * DD + sub * 8;
        const f32x4 t0 = __builtin_nontemporal_load(reinterpret_cast<const f32x4*>(blend + bi));
        const f32x4 t1 = __builtin_nontemporal_load(reinterpret_cast<const f32x4*>(blend + bi + 4));
        f16x8 o;
        o[0] = (_Float16)(0.5f * fmaxf(acc[0], 0.f) + 0.5f * t0[0]);
        o[1] = (_Float16)(0.5f * fmaxf(acc[1], 0.f) + 0.5f * t0[1]);
        o[2] = (_Float16)(0.5f * fmaxf(acc[2], 0.f) + 0.5f * t0[2]);
        o[3] = (_Float16)(0.5f * fmaxf(acc[3], 0.f) + 0.5f * t0[3]);
        o[4] = (_Float16)(0.5f * fmaxf(acc[4], 0.f) + 0.5f * t1[0]);
        o[5] = (_Float16)(0.5f * fmaxf(acc[5], 0.f) + 0.5f * t1[1]);
        o[6] = (_Float16)(0.5f * fmaxf(acc[6], 0.f) + 0.5f * t1[2]);
        o[7] = (_Float16)(0.5f * fmaxf(acc[7], 0.f) + 0.5f * t1[3]);
        *reinterpret_cast<f16x8*>(Xout + bi) = o;
    }
}

// Last layer: fused agg -> blend(z) -> Y5 = blended @ W5 (fp32) and q columns.
__global__ __launch_bounds__(256) void k_spmm_last(const int* __restrict__ offs,
                                                   const unsigned* __restrict__ edges,
                                                   const _Float16* __restrict__ Y,
                                                   const float* __restrict__ z,
                                                   const float* __restrict__ W5,
                                                   const float* __restrict__ cl,
                                                   float* __restrict__ Y5,
                                                   float* __restrict__ out) {
    const int row = blockIdx.x * 4 + (threadIdx.x >> 6);
    if (row >= NN) return;
    const int lane = threadIdx.x & 63;
    const int half = lane >> 5;
    const int sub = lane & 31;
    const int e0 = offs[row], e1 = offs[row + 1];
    float acc[8] = {};
    int e = e0 + half;
    for (; e + 6 < e1; e += 8) {
        const unsigned u0 = edges[e], u1 = edges[e + 2], u2 = edges[e + 4], u3 = edges[e + 6];
        const float v0 = (float)(u0 >> 17) * INV15;
        const float v1 = (float)(u1 >> 17) * INV15;
        const float v2 = (float)(u2 >> 17) * INV15;
        const float v3 = (float)(u3 >> 17) * INV15;
        const f16x8 y0 = *reinterpret_cast<const f16x8*>(Y + ((size_t)(u0 & 0x1FFFFu) << 8) + sub * 8);
        const f16x8 y1 = *reinterpret_cast<const f16x8*>(Y + ((size_t)(u1 & 0x1FFFFu) << 8) + sub * 8);
        const f16x8 y2 = *reinterpret_cast<const f16x8*>(Y + ((size_t)(u2 & 0x1FFFFu) << 8) + sub * 8);
        const f16x8 y3 = *reinterpret_cast<const f16x8*>(Y + ((size_t)(u3 & 0x1FFFFu) << 8) + sub * 8);
#pragma unroll
        for (int j = 0; j < 8; ++j)
            acc[j] += v0 * (float)y0[j] + v1 * (float)y1[j] + v2 * (float)y2[j] + v3 * (float)y3[j];
    }
    for (; e < e1; e += 2) {
        const unsigned u = edges[e];
        const float v = (float)(u >> 17) * INV15;
        const f16x8 y = *reinterpret_cast<const f16x8*>(Y + ((size_t)(u & 0x1FFFFu) << 8) + sub * 8);
#pragma unroll
        for (int j = 0; j < 8; ++j) acc[j] += v * (float)y[j];
    }
#pragma unroll
    for (int j = 0; j < 8; ++j) acc[j] += __shfl_xor(acc[j], 32);
    if (half == 0) {
        const size_t bi = (size_t)row * DD + sub * 8;
        const f32x4 z0 = __builtin_nontemporal_load(reinterpret_cast<const f32x4*>(z + bi));
        const f32x4 z1 = __builtin_nontemporal_load(reinterpret_cast<const f32x4*>(z + bi + 4));
        const float zb[8] = {z0[0], z0[1], z0[2], z0[3], z1[0], z1[1], z1[2], z1[3]};
        float p[4] = {0.f, 0.f, 0.f, 0.f};
        float zz = 0.f;
#pragma unroll
        for (int j = 0; j < 8; ++j) {
            const float b = 0.5f * fmaxf(acc[j], 0.f) + 0.5f * zb[j];
            const f32x4 w = *reinterpret_cast<const f32x4*>(W5 + (size_t)(sub * 8 + j) * KC);
            p[0] += b * w[0];
            p[1] += b * w[1];
            p[2] += b * w[2];
            p[3] += b * w[3];
            zz += zb[j] * zb[j];
        }
        float dot[4] = {0.f, 0.f, 0.f, 0.f}, cc[4] = {0.f, 0.f, 0.f, 0.f};
#pragma unroll
        for (int c2 = 0; c2 < 4; ++c2) {
            const f32x4 c40 = *reinterpret_cast<const f32x4*>(cl + (size_t)c2 * DD + sub * 8);
            const f32x4 c41 = *reinterpret_cast<const f32x4*>(cl + (size_t)c2 * DD + sub * 8 + 4);
            dot[c2] = zb[0] * c40[0] + zb[1] * c40[1] + zb[2] * c40[2] + zb[3] * c40[3] +
                      zb[4] * c41[0] + zb[5] * c41[1] + zb[6] * c41[2] + zb[7] * c41[3];
            cc[c2] = c40[0] * c40[0] + c40[1] * c40[1] + c40[2] * c40[2] + c40[3] * c40[3] +
                     c41[0] * c41[0] + c41[1] * c41[1] + c41[2] * c41[2] + c41[3] * c41[3];
        }
#pragma unroll
        for (int o = 16; o; o >>= 1) {
            zz += __shfl_xor(zz, o);
#pragma unroll
            for (int c2 = 0; c2 < 4; ++c2) {
                p[c2] += __shfl_xor(p[c2], o);
                dot[c2] += __shfl_xor(dot[c2], o);
                cc[c2] += __shfl_xor(cc[c2], o);
            }
        }
        if (sub == 0) {
            *reinterpret_cast<f32x4*>(Y5 + (size_t)row * KC) = (f32x4){p[0], p[1], p[2], p[3]};
            float q[4], s = 0.f;
#pragma unroll
            for (int c2 = 0; c2 < 4; ++c2) {
                const float d2 = zz - 2.f * dot[c2] + cc[c2];
                q[c2] = 1.f / (1.f + d2);
                s += q[c2];
            }
            const float inv = 1.f / s;
            *reinterpret_cast<f32x4*>(out + (size_t)row * 8 + 4) =
                (f32x4){q[0] * inv, q[1] * inv, q[2] * inv, q[3] * inv};
        }
    }
}

// ---------------------------------------------------------------- softmax tail

__device__ inline float wred(float v) {
#pragma unroll
    for (int o = 32; o; o >>= 1) v += __shfl_down(v, o);
    return v;
}

__global__ __launch_bounds__(256) void k_sm5(const int* __restrict__ offs,
                                             const unsigned* __restrict__ edges,
                                             const float* __restrict__ Y5,
                                             float* __restrict__ out) {
    const int row = blockIdx.x * 4 + (threadIdx.x >> 6);
    if (row >= NN) return;
    const int lane = threadIdx.x & 63;
    const int e0 = offs[row], e1 = offs[row + 1];
    float ax = 0.f, ay = 0.f, az = 0.f, aw = 0.f;
    for (int e = e0 + lane; e < e1; e += 64) {
        const unsigned u = edges[e];
        const float v = (float)(u >> 17) * INV15;
        const f32x4 y = *reinterpret_cast<const f32x4*>(Y5 + (size_t)(u & 0x1FFFFu) * KC);
        ax += v * y[0];
        ay += v * y[1];
        az += v * y[2];
        aw += v * y[3];
    }
    ax = wred(ax);
    ay = wred(ay);
    az = wred(az);
    aw = wred(aw);
    if (lane == 0) {
        float m = fmaxf(fmaxf(ax, ay), fmaxf(az, aw));
        float ex = __expf(ax - m), ey = __expf(ay - m), ez = __expf(az - m), ew = __expf(aw - m);
        float inv = 1.f / (ex + ey + ez + ew);
        *reinterpret_cast<f32x4*>(out + (size_t)row * 8) =
            (f32x4){ex * inv, ey * inv, ez * inv, ew * inv};
    }
}

// ---------------------------------------------------------------- launch

extern "C" void kernel_launch(void* const* d_in, const int* in_sizes, int n_in,
                              void* d_out, int out_size, void* d_ws, size_t ws_size,
                              hipStream_t stream) {
    const float* enc = (const float*)d_in[0];
    const float* tra1 = (const float*)d_in[1];
    const float* tra2 = (const float*)d_in[2];
    const float* tra3 = (const float*)d_in[3];
    const float* z = (const float*)d_in[4];
    const int* erow = (const int*)d_in[5];
    const int* ecol = (const int*)d_in[6];
    const float* evals = (const float*)d_in[7];
    const float* W1 = (const float*)d_in[8];
    const float* W2 = (const float*)d_in[9];
    const float* W3 = (const float*)d_in[10];
    const float* W4 = (const float*)d_in[11];
    const float* W5 = (const float*)d_in[12];
    const float* cluster = (const float*)d_in[13];
    float* out = (float*)d_out;

    char* ws = (char*)d_ws;
    size_t off = 0;
    auto take = [&](size_t bytes) -> void* {
        void* p = ws + off;
        off = (off + bytes + 255) & ~(size_t)255;
        return p;
    };
    int* counts = (int*)take((size_t)NN * 4);
    int* cursor = (int*)take((size_t)NN * 4);
    int* offs = (int*)take((size_t)(NN + 1) * 4);
    int* bsum = (int*)take(4096);
    int* bcur = (int*)take((size_t)NBUK * 4);
    int2* recs = (int2*)take((size_t)NE * 8);
    unsigned* edges = (unsigned*)take((size_t)NE * 4);
    _Float16* Xa = (_Float16*)take((size_t)MPAD * DD * 2);
    _Float16* Xb = (_Float16*)take((size_t)MPAD * DD * 2);
    _Float16* Wt = (_Float16*)take((size_t)4 * DD * DD * 2);
    float* Y5 = (float*)take((size_t)NN * KC * 4);

    hipMemsetAsync(counts, 0, (size_t)NN * 4, stream);
    hipMemsetAsync(cursor, 0, (size_t)NN * 4, stream);

    k_hist<<<(NE + 255) / 256, 256, 0, stream>>>(erow, counts);
    const int nsb = (NN + 1023) / 1024;  // 98
    k_scan1<<<nsb, 256, 0, stream>>>(counts, offs, bsum);
    k_scan2<<<1, 64, 0, stream>>>(bsum, nsb);
    k_scan3<<<(NN + 256) / 256, 256, 0, stream>>>(offs, bsum);
    k_initb<<<(NBUK + 255) / 256, 256, 0, stream>>>(offs, bcur);
    k_bin<<<(NE + 255) / 256, 256, 0, stream>>>(erow, ecol, evals, bcur, recs);
    k_place<<<NBUK, 256, 0, stream>>>(recs, offs, cursor, edges);

    k_cvtX<<<(NN * DD / 8 + 255) / 256, 256, 0, stream>>>(enc, Xa);
    k_cvtW<<<dim3(8, 8, 4), 256, 0, stream>>>(W1, W2, W3, W4, Wt);

    const int gb = MPAD / 128;  // 782
    const int rb = NN / 4;      // 25000

    k_gemm_h<<<gb, 512, 0, stream>>>(Xa, Wt + 0 * DD * DD, Xb);
    k_spmm_h<<<rb, 256, 0, stream>>>(offs, edges, Xb, tra1, Xa);

    k_gemm_h<<<gb, 512, 0, stream>>>(Xa, Wt + 1 * DD * DD, Xb);
    k_spmm_h<<<rb, 256, 0, stream>>>(offs, edges, Xb, tra2, Xa);

    k_gemm_h<<<gb, 512, 0, stream>>>(Xa, Wt + 2 * DD * DD, Xb);
    k_spmm_h<<<rb, 256, 0, stream>>>(offs, edges, Xb, tra3, Xa);

    k_gemm_h<<<gb, 512, 0, stream>>>(Xa, Wt + 3 * DD * DD, Xb);
    k_spmm_last<<<rb, 256, 0, stream>>>(offs, edges, Xb, z, W5, cluster, Y5, out);

    k_sm5<<<rb, 256, 0, stream>>>(offs, edges, Y5, out);
}

// Round 7
// 1564.089 us; speedup vs baseline: 1.5343x; 1.5343x over previous
//
#include <hip/hip_runtime.h>

#define NN 100000
#define NE 3200000
#define DD 256
#define KC 4
#define MPAD 100096  // 782 * 128
#define NBUK ((NN + 255) >> 8)   // 391 buckets of 256 rows
#define NSUB 64
#define NS (NBUK * NSUB)         // 25024 sub-cursors
#define INV15 (1.0f / 32767.0f)

typedef _Float16 f16x8 __attribute__((ext_vector_type(8)));
typedef float f32x4 __attribute__((ext_vector_type(4)));

// ---------------------------------------------------------------- CSR build

// fused: per-row counts + per-(bucket,sub) counts. sub = blockIdx&63 must match k_bin.
__global__ __launch_bounds__(256) void k_hist(const int* __restrict__ row,
                                              int* __restrict__ counts,
                                              int* __restrict__ h2) {
    int e = blockIdx.x * 256 + threadIdx.x;
    if (e >= NE) return;
    int r = row[e];
    atomicAdd(&counts[r], 1);
    atomicAdd(&h2[(r >> 8) * NSUB + (blockIdx.x & (NSUB - 1))], 1);
}

// generic scan: blocks of 1024 (256 thr x 4 items)
__global__ __launch_bounds__(256) void k_scan1g(const int* __restrict__ in,
                                                int* __restrict__ out,
                                                int* __restrict__ bsum, int n) {
    __shared__ int s[256];
    const int t = threadIdx.x;
    const int base = blockIdx.x * 1024 + t * 4;
    int v[4];
    int sum = 0;
#pragma unroll
    for (int i = 0; i < 4; ++i) {
        v[i] = (base + i < n) ? in[base + i] : 0;
        sum += v[i];
    }
    s[t] = sum;
    __syncthreads();
    for (int off = 1; off < 256; off <<= 1) {
        int x = (t >= off) ? s[t - off] : 0;
        __syncthreads();
        s[t] += x;
        __syncthreads();
    }
    int run = (t > 0) ? s[t - 1] : 0;
#pragma unroll
    for (int i = 0; i < 4; ++i) {
        if (base + i < n) out[base + i] = run;
        run += v[i];
    }
    if (t == 255) bsum[blockIdx.x] = s[255];
}

__global__ void k_scan2(int* __restrict__ bsum, int nb) {
    if (threadIdx.x == 0 && blockIdx.x == 0) {
        int run = 0;
        for (int i = 0; i < nb; ++i) {
            int c = bsum[i];
            bsum[i] = run;
            run += c;
        }
    }
}

__global__ __launch_bounds__(256) void k_scan3g(int* __restrict__ out,
                                                const int* __restrict__ bsum,
                                                int n, int total) {
    int i = blockIdx.x * 256 + threadIdx.x;
    if (i < n)
        out[i] += bsum[i >> 10];
    else if (i == n)
        out[n] = total;
}

// pass 1: bin edges into bucket windows via 64 sub-cursors per bucket
// (sub-segment bases pre-scanned in s2cur; sequential bump per sub-cursor)
__global__ __launch_bounds__(256) void k_bin(const int* __restrict__ row,
                                             const int* __restrict__ col,
                                             const float* __restrict__ val,
                                             int* __restrict__ s2cur,
                                             int2* __restrict__ recs) {
    int e = blockIdx.x * 256 + threadIdx.x;
    if (e >= NE) return;
    int r = row[e];
    unsigned v15 = (unsigned)(val[e] * 32767.f + 0.5f);
    unsigned packed = (v15 << 17) | (unsigned)col[e];
    int p = atomicAdd(&s2cur[(r >> 8) * NSUB + (blockIdx.x & (NSUB - 1))], 1);
    int2 rec;
    rec.x = (int)packed;
    rec.y = r;
    recs[p] = rec;
}

// pass 2: one workgroup per bucket; LDS row-cursors; scatter into 32KB window.
__global__ __launch_bounds__(256) void k_place(const int2* __restrict__ recs,
                                               const int* __restrict__ offs,
                                               unsigned* __restrict__ edges) {
    __shared__ int lcur[256];
    const int b = blockIdx.x;
    const int lo = b << 8;
    const int hi = min(lo + 256, NN);
    const int nr = hi - lo;
    if (threadIdx.x < nr) lcur[threadIdx.x] = offs[lo + threadIdx.x];
    __syncthreads();
    const int base = offs[lo];
    const int end = offs[hi];
    for (int i = base + (int)threadIdx.x; i < end; i += 256) {
        const int2 rec = recs[i];
        const int p = atomicAdd(&lcur[rec.y - lo], 1);
        edges[p] = (unsigned)rec.x;
    }
}

// ---------------------------------------------------------------- fp16 converts

__global__ __launch_bounds__(256) void k_cvtX(const float* __restrict__ in,
                                              _Float16* __restrict__ out) {
    const size_t base = ((size_t)blockIdx.x * 256 + threadIdx.x) * 8;
    if (base >= (size_t)NN * DD) return;
    f32x4 v0 = __builtin_nontemporal_load(reinterpret_cast<const f32x4*>(in + base));
    f32x4 v1 = __builtin_nontemporal_load(reinterpret_cast<const f32x4*>(in + base + 4));
    f16x8 o;
    o[0] = (_Float16)v0[0]; o[1] = (_Float16)v0[1]; o[2] = (_Float16)v0[2]; o[3] = (_Float16)v0[3];
    o[4] = (_Float16)v1[0]; o[5] = (_Float16)v1[1]; o[6] = (_Float16)v1[2]; o[7] = (_Float16)v1[3];
    *reinterpret_cast<f16x8*>(out + base) = o;
}

__global__ __launch_bounds__(256) void k_cvtW(const float* __restrict__ W1,
                                              const float* __restrict__ W2,
                                              const float* __restrict__ W3,
                                              const float* __restrict__ W4,
                                              _Float16* __restrict__ Wt) {
    __shared__ float s[32][33];
    const float* W = (blockIdx.z == 0) ? W1 : (blockIdx.z == 1) ? W2 : (blockIdx.z == 2) ? W3 : W4;
    _Float16* o = Wt + (size_t)blockIdx.z * DD * DD;
    const int bk = blockIdx.x * 32;
    const int bn = blockIdx.y * 32;
    const int tx = threadIdx.x & 31, ty = threadIdx.x >> 5;
    for (int r = ty; r < 32; r += 8) s[r][tx] = W[(size_t)(bk + r) * DD + bn + tx];
    __syncthreads();
    for (int r = ty; r < 32; r += 8) o[(size_t)(bn + r) * DD + bk + tx] = (_Float16)s[tx][r];
}

// ---------------------------------------------------------------- GEMM fp16 MFMA

__device__ __forceinline__ void load_lds16(const void* g, void* l) {
    __builtin_amdgcn_global_load_lds((const __attribute__((address_space(1))) void*)g,
                                     (__attribute__((address_space(3))) void*)l, 16, 0, 0);
}

__global__ __launch_bounds__(512, 4) void k_gemm_h(const _Float16* __restrict__ X,
                                                   const _Float16* __restrict__ Wt,
                                                   _Float16* __restrict__ Y) {
    __shared__ __align__(16) char lds[49152];  // A[2][8192] | B[2][16384]
    char* const Albase = lds;
    char* const Blbase = lds + 16384;

    const int tid = threadIdx.x;
    const int lane = tid & 63;
    const int wid = tid >> 6;
    const int wr = wid >> 2;
    const int wc = wid & 3;
    const int bm = blockIdx.x * 128;

    const int aoffl = wid * 1024 + lane * 16;
    const int arw = aoffl >> 6;
    const int acb = (aoffl & 63) ^ (((arw >> 1) & 3) << 4);
    const char* const Asrc0 = (const char*)X + ((size_t)(bm + arw) * DD) * 2 + acb;
    char* const Adst0 = Albase + wid * 1024;

    const int boffl0 = wid * 1024 + lane * 16;
    const int brw0 = boffl0 >> 6;
    const int bcb0 = (boffl0 & 63) ^ (((brw0 >> 1) & 3) << 4);
    const char* const Bsrc0 = (const char*)Wt + ((size_t)brw0 * DD) * 2 + bcb0;
    const int boffl1 = 8192 + wid * 1024 + lane * 16;
    const int brw1 = boffl1 >> 6;
    const int bcb1 = (boffl1 & 63) ^ (((brw1 >> 1) & 3) << 4);
    const char* const Bsrc1 = (const char*)Wt + ((size_t)brw1 * DD) * 2 + bcb1;
    char* const Bdst0 = Blbase + wid * 1024;
    char* const Bdst1 = Blbase + 8192 + wid * 1024;

    int aro[4], bro[4];
#pragma unroll
    for (int m = 0; m < 4; ++m) {
        const int r = wr * 64 + m * 16 + (lane & 15);
        aro[m] = r * 64 + ((((lane >> 4) * 16)) ^ (((r >> 1) & 3) << 4));
    }
#pragma unroll
    for (int n = 0; n < 4; ++n) {
        const int r = wc * 64 + n * 16 + (lane & 15);
        bro[n] = r * 64 + ((((lane >> 4) * 16)) ^ (((r >> 1) & 3) << 4));
    }

    f32x4 acc[4][4];
#pragma unroll
    for (int m = 0; m < 4; ++m)
#pragma unroll
        for (int n = 0; n < 4; ++n) acc[m][n] = (f32x4){0.f, 0.f, 0.f, 0.f};

    load_lds16(Asrc0, Adst0);
    load_lds16(Bsrc0, Bdst0);
    load_lds16(Bsrc1, Bdst1);
    __syncthreads();

    for (int kt = 0; kt < 8; ++kt) {
        const int cur = kt & 1;
        if (kt < 7) {
            const size_t kb = (size_t)(kt + 1) * 32 * 2;
            load_lds16(Asrc0 + kb, Adst0 + (cur ^ 1) * 8192);
            load_lds16(Bsrc0 + kb, Bdst0 + (cur ^ 1) * 16384);
            load_lds16(Bsrc1 + kb, Bdst1 + (cur ^ 1) * 16384);
        }
        const char* Ab = Albase + cur * 8192;
        const char* Bb = Blbase + cur * 16384;
        f16x8 af[4], bf[4];
#pragma unroll
        for (int m = 0; m < 4; ++m) af[m] = *reinterpret_cast<const f16x8*>(Ab + aro[m]);
#pragma unroll
        for (int n = 0; n < 4; ++n) bf[n] = *reinterpret_cast<const f16x8*>(Bb + bro[n]);
#pragma unroll
        for (int m = 0; m < 4; ++m)
#pragma unroll
            for (int n = 0; n < 4; ++n)
                acc[m][n] = __builtin_amdgcn_mfma_f32_16x16x32_f16(af[m], bf[n], acc[m][n], 0, 0, 0);
        __syncthreads();
    }

#pragma unroll
    for (int m = 0; m < 4; ++m) {
        const int row = bm + wr * 64 + m * 16 + (lane >> 4) * 4;
#pragma unroll
        for (int n = 0; n < 4; ++n) {
            const int col = wc * 64 + n * 16 + (lane & 15);
#pragma unroll
            for (int j = 0; j < 4; ++j)
                Y[(size_t)(row + j) * DD + col] = (_Float16)acc[m][n][j];
        }
    }
}

// ---------------------------------------------------------------- SpMM fp16 (full D)

__global__ __launch_bounds__(256) void k_spmm_h(const int* __restrict__ offs,
                                                const unsigned* __restrict__ edges,
                                                const _Float16* __restrict__ Y,
                                                const float* __restrict__ blend,
                                                _Float16* __restrict__ Xout) {
    const int row = blockIdx.x * 4 + (threadIdx.x >> 6);
    if (row >= NN) return;
    const int lane = threadIdx.x & 63;
    const int half = lane >> 5;
    const int sub = lane & 31;
    const int e0 = offs[row], e1 = offs[row + 1];
    float acc[8] = {};
    int e = e0 + half;
    for (; e + 6 < e1; e += 8) {
        const unsigned u0 = edges[e], u1 = edges[e + 2], u2 = edges[e + 4], u3 = edges[e + 6];
        const float v0 = (float)(u0 >> 17) * INV15;
        const float v1 = (float)(u1 >> 17) * INV15;
        const float v2 = (float)(u2 >> 17) * INV15;
        const float v3 = (float)(u3 >> 17) * INV15;
        const f16x8 y0 = *reinterpret_cast<const f16x8*>(Y + ((size_t)(u0 & 0x1FFFFu) << 8) + sub * 8);
        const f16x8 y1 = *reinterpret_cast<const f16x8*>(Y + ((size_t)(u1 & 0x1FFFFu) << 8) + sub * 8);
        const f16x8 y2 = *reinterpret_cast<const f16x8*>(Y + ((size_t)(u2 & 0x1FFFFu) << 8) + sub * 8);
        const f16x8 y3 = *reinterpret_cast<const f16x8*>(Y + ((size_t)(u3 & 0x1FFFFu) << 8) + sub * 8);
#pragma unroll
        for (int j = 0; j < 8; ++j)
            acc[j] += v0 * (float)y0[j] + v1 * (float)y1[j] + v2 * (float)y2[j] + v3 * (float)y3[j];
    }
    for (; e < e1; e += 2) {
        const unsigned u = edges[e];
        const float v = (float)(u >> 17) * INV15;
        const f16x8 y = *reinterpret_cast<const f16x8*>(Y + ((size_t)(u & 0x1FFFFu) << 8) + sub * 8);
#pragma unroll
        for (int j = 0; j < 8; ++j) acc[j] += v * (float)y[j];
    }
#pragma unroll
    for (int j = 0; j < 8; ++j) acc[j] += __shfl_xor(acc[j], 32);
    if (half == 0) {
        const size_t bi = (size_t)row * DD + sub * 8;
        const f32x4 t0 = __builtin_nontemporal_load(reinterpret_cast<const f32x4*>(blend + bi));
        const f32x4 t1 = __builtin_nontemporal_load(reinterpret_cast<const f32x4*>(blend + bi + 4));
        f16x8 o;
        o[0] = (_Float16)(0.5f * fmaxf(acc[0], 0.f) + 0.5f * t0[0]);
        o[1] = (_Float16)(0.5f * fmaxf(acc[1], 0.f) + 0.5f * t0[1]);
        o[2] = (_Float16)(0.5f * fmaxf(acc[2], 0.f) + 0.5f * t0[2]);
        o[3] = (_Float16)(0.5f * fmaxf(acc[3], 0.f) + 0.5f * t0[3]);
        o[4] = (_Float16)(0.5f * fmaxf(acc[4], 0.f) + 0.5f * t1[0]);
        o[5] = (_Float16)(0.5f * fmaxf(acc[5], 0.f) + 0.5f * t1[1]);
        o[6] = (_Float16)(0.5f * fmaxf(acc[6], 0.f) + 0.5f * t1[2]);
        o[7] = (_Float16)(0.5f * fmaxf(acc[7], 0.f) + 0.5f * t1[3]);
        *reinterpret_cast<f16x8*>(Xout + bi) = o;
    }
}

// Last layer: fused agg -> blend(z) -> Y5 = blended @ W5 (fp32) and q columns.
__global__ __launch_bounds__(256) void k_spmm_last(const int* __restrict__ offs,
                                                   const unsigned* __restrict__ edges,
                                                   const _Float16* __restrict__ Y,
                                                   const float* __restrict__ z,
                                                   const float* __restrict__ W5,
                                                   const float* __restrict__ cl,
                                                   float* __restrict__ Y5,
                                                   float* __restrict__ out) {
    const int row = blockIdx.x * 4 + (threadIdx.x >> 6);
    if (row >= NN) return;
    const int lane = threadIdx.x & 63;
    const int half = lane >> 5;
    const int sub = lane & 31;
    const int e0 = offs[row], e1 = offs[row + 1];
    float acc[8] = {};
    int e = e0 + half;
    for (; e + 6 < e1; e += 8) {
        const unsigned u0 = edges[e], u1 = edges[e + 2], u2 = edges[e + 4], u3 = edges[e + 6];
        const float v0 = (float)(u0 >> 17) * INV15;
        const float v1 = (float)(u1 >> 17) * INV15;
        const float v2 = (float)(u2 >> 17) * INV15;
        const float v3 = (float)(u3 >> 17) * INV15;
        const f16x8 y0 = *reinterpret_cast<const f16x8*>(Y + ((size_t)(u0 & 0x1FFFFu) << 8) + sub * 8);
        const f16x8 y1 = *reinterpret_cast<const f16x8*>(Y + ((size_t)(u1 & 0x1FFFFu) << 8) + sub * 8);
        const f16x8 y2 = *reinterpret_cast<const f16x8*>(Y + ((size_t)(u2 & 0x1FFFFu) << 8) + sub * 8);
        const f16x8 y3 = *reinterpret_cast<const f16x8*>(Y + ((size_t)(u3 & 0x1FFFFu) << 8) + sub * 8);
#pragma unroll
        for (int j = 0; j < 8; ++j)
            acc[j] += v0 * (float)y0[j] + v1 * (float)y1[j] + v2 * (float)y2[j] + v3 * (float)y3[j];
    }
    for (; e < e1; e += 2) {
        const unsigned u = edges[e];
        const float v = (float)(u >> 17) * INV15;
        const f16x8 y = *reinterpret_cast<const f16x8*>(Y + ((size_t)(u & 0x1FFFFu) << 8) + sub * 8);
#pragma unroll
        for (int j = 0; j < 8; ++j) acc[j] += v * (float)y[j];
    }
#pragma unroll
    for (int j = 0; j < 8; ++j) acc[j] += __shfl_xor(acc[j], 32);
    if (half == 0) {
        const size_t bi = (size_t)row * DD + sub * 8;
        const f32x4 z0 = __builtin_nontemporal_load(reinterpret_cast<const f32x4*>(z + bi));
        const f32x4 z1 = __builtin_nontemporal_load(reinterpret_cast<const f32x4*>(z + bi + 4));
        const float zb[8] = {z0[0], z0[1], z0[2], z0[3], z1[0], z1[1], z1[2], z1[3]};
        float p[4] = {0.f, 0.f, 0.f, 0.f};
        float zz = 0.f;
#pragma unroll
        for (int j = 0; j < 8; ++j) {
            const float b = 0.5f * fmaxf(acc[j], 0.f) + 0.5f * zb[j];
            const f32x4 w = *reinterpret_cast<const f32x4*>(W5 + (size_t)(sub * 8 + j) * KC);
            p[0] += b * w[0];
            p[1] += b * w[1];
            p[2] += b * w[2];
            p[3] += b * w[3];
            zz += zb[j] * zb[j];
        }
        float dot[4] = {0.f, 0.f, 0.f, 0.f}, cc[4] = {0.f, 0.f, 0.f, 0.f};
#pragma unroll
        for (int c2 = 0; c2 < 4; ++c2) {
            const f32x4 c40 = *reinterpret_cast<const f32x4*>(cl + (size_t)c2 * DD + sub * 8);
            const f32x4 c41 = *reinterpret_cast<const f32x4*>(cl + (size_t)c2 * DD + sub * 8 + 4);
            dot[c2] = zb[0] * c40[0] + zb[1] * c40[1] + zb[2] * c40[2] + zb[3] * c40[3] +
                      zb[4] * c41[0] + zb[5] * c41[1] + zb[6] * c41[2] + zb[7] * c41[3];
            cc[c2] = c40[0] * c40[0] + c40[1] * c40[1] + c40[2] * c40[2] + c40[3] * c40[3] +
                     c41[0] * c41[0] + c41[1] * c41[1] + c41[2] * c41[2] + c41[3] * c41[3];
        }
#pragma unroll
        for (int o = 16; o; o >>= 1) {
            zz += __shfl_xor(zz, o);
#pragma unroll
            for (int c2 = 0; c2 < 4; ++c2) {
                p[c2] += __shfl_xor(p[c2], o);
                dot[c2] += __shfl_xor(dot[c2], o);
                cc[c2] += __shfl_xor(cc[c2], o);
            }
        }
        if (sub == 0) {
            *reinterpret_cast<f32x4*>(Y5 + (size_t)row * KC) = (f32x4){p[0], p[1], p[2], p[3]};
            float q[4], s = 0.f;
#pragma unroll
            for (int c2 = 0; c2 < 4; ++c2) {
                const float d2 = zz - 2.f * dot[c2] + cc[c2];
                q[c2] = 1.f / (1.f + d2);
                s += q[c2];
            }
            const float inv = 1.f / s;
            *reinterpret_cast<f32x4*>(out + (size_t)row * 8 + 4) =
                (f32x4){q[0] * inv, q[1] * inv, q[2] * inv, q[3] * inv};
        }
    }
}

// ---------------------------------------------------------------- softmax tail

__device__ inline float wred(float v) {
#pragma unroll
    for (int o = 32; o; o >>= 1) v += __shfl_down(v, o);
    return v;
}

__global__ __launch_bounds__(256) void k_sm5(const int* __restrict__ offs,
                                             const unsigned* __restrict__ edges,
                                             const float* __restrict__ Y5,
                                             float* __restrict__ out) {
    const int row = blockIdx.x * 4 + (threadIdx.x >> 6);
    if (row >= NN) return;
    const int lane = threadIdx.x & 63;
    const int e0 = offs[row], e1 = offs[row + 1];
    float ax = 0.f, ay = 0.f, az = 0.f, aw = 0.f;
    for (int e = e0 + lane; e < e1; e += 64) {
        const unsigned u = edges[e];
        const float v = (float)(u >> 17) * INV15;
        const f32x4 y = *reinterpret_cast<const f32x4*>(Y5 + (size_t)(u & 0x1FFFFu) * KC);
        ax += v * y[0];
        ay += v * y[1];
        az += v * y[2];
        aw += v * y[3];
    }
    ax = wred(ax);
    ay = wred(ay);
    az = wred(az);
    aw = wred(aw);
    if (lane == 0) {
        float m = fmaxf(fmaxf(ax, ay), fmaxf(az, aw));
        float ex = __expf(ax - m), ey = __expf(ay - m), ez = __expf(az - m), ew = __expf(aw - m);
        float inv = 1.f / (ex + ey + ez + ew);
        *reinterpret_cast<f32x4*>(out + (size_t)row * 8) =
            (f32x4){ex * inv, ey * inv, ez * inv, ew * inv};
    }
}

// ---------------------------------------------------------------- launch

extern "C" void kernel_launch(void* const* d_in, const int* in_sizes, int n_in,
                              void* d_out, int out_size, void* d_ws, size_t ws_size,
                              hipStream_t stream) {
    const float* enc = (const float*)d_in[0];
    const float* tra1 = (const float*)d_in[1];
    const float* tra2 = (const float*)d_in[2];
    const float* tra3 = (const float*)d_in[3];
    const float* z = (const float*)d_in[4];
    const int* erow = (const int*)d_in[5];
    const int* ecol = (const int*)d_in[6];
    const float* evals = (const float*)d_in[7];
    const float* W1 = (const float*)d_in[8];
    const float* W2 = (const float*)d_in[9];
    const float* W3 = (const float*)d_in[10];
    const float* W4 = (const float*)d_in[11];
    const float* W5 = (const float*)d_in[12];
    const float* cluster = (const float*)d_in[13];
    float* out = (float*)d_out;

    char* ws = (char*)d_ws;
    size_t off = 0;
    auto take = [&](size_t bytes) -> void* {
        void* p = ws + off;
        off = (off + bytes + 255) & ~(size_t)255;
        return p;
    };
    int* counts = (int*)take((size_t)NN * 4);
    int* offs = (int*)take((size_t)(NN + 1) * 4);
    int* h2 = (int*)take((size_t)NS * 4);
    int* s2cur = (int*)take((size_t)(NS + 1) * 4);
    int* bsum = (int*)take(4096);
    int2* recs = (int2*)take((size_t)NE * 8);
    unsigned* edges = (unsigned*)take((size_t)NE * 4);
    _Float16* Xa = (_Float16*)take((size_t)MPAD * DD * 2);
    _Float16* Xb = (_Float16*)take((size_t)MPAD * DD * 2);
    _Float16* Wt = (_Float16*)take((size_t)4 * DD * DD * 2);
    float* Y5 = (float*)take((size_t)NN * KC * 4);

    hipMemsetAsync(counts, 0, (size_t)NN * 4, stream);
    hipMemsetAsync(h2, 0, (size_t)NS * 4, stream);

    k_hist<<<(NE + 255) / 256, 256, 0, stream>>>(erow, counts, h2);

    // scan row counts -> offs
    const int nb1 = (NN + 1023) / 1024;  // 98
    k_scan1g<<<nb1, 256, 0, stream>>>(counts, offs, bsum, NN);
    k_scan2<<<1, 64, 0, stream>>>(bsum, nb1);
    k_scan3g<<<(NN + 256) / 256, 256, 0, stream>>>(offs, bsum, NN, NE);

    // scan sub-cursor counts -> s2cur (bucket-major, aligns with offs at bucket bounds)
    const int nb2 = (NS + 1023) / 1024;  // 25
    k_scan1g<<<nb2, 256, 0, stream>>>(h2, s2cur, bsum, NS);
    k_scan2<<<1, 64, 0, stream>>>(bsum, nb2);
    k_scan3g<<<(NS + 256) / 256, 256, 0, stream>>>(s2cur, bsum, NS, NE);

    k_bin<<<(NE + 255) / 256, 256, 0, stream>>>(erow, ecol, evals, s2cur, recs);
    k_place<<<NBUK, 256, 0, stream>>>(recs, offs, edges);

    k_cvtX<<<(NN * DD / 8 + 255) / 256, 256, 0, stream>>>(enc, Xa);
    k_cvtW<<<dim3(8, 8, 4), 256, 0, stream>>>(W1, W2, W3, W4, Wt);

    const int gb = MPAD / 128;  // 782
    const int rb = NN / 4;      // 25000

    k_gemm_h<<<gb, 512, 0, stream>>>(Xa, Wt + 0 * DD * DD, Xb);
    k_spmm_h<<<rb, 256, 0, stream>>>(offs, edges, Xb, tra1, Xa);

    k_gemm_h<<<gb, 512, 0, stream>>>(Xa, Wt + 1 * DD * DD, Xb);
    k_spmm_h<<<rb, 256, 0, stream>>>(offs, edges, Xb, tra2, Xa);

    k_gemm_h<<<gb, 512, 0, stream>>>(Xa, Wt + 2 * DD * DD, Xb);
    k_spmm_h<<<rb, 256, 0, stream>>>(offs, edges, Xb, tra3, Xa);

    k_gemm_h<<<gb, 512, 0, stream>>>(Xa, Wt + 3 * DD * DD, Xb);
    k_spmm_last<<<rb, 256, 0, stream>>>(offs, edges, Xb, z, W5, cluster, Y5, out);

    k_sm5<<<rb, 256, 0, stream>>>(offs, edges, Y5, out);
}

// Round 8
// 1194.383 us; speedup vs baseline: 2.0092x; 1.3095x over previous
//
#include <hip/hip_runtime.h>

#define NN 100000
#define NE 3200000
#define DD 256
#define KC 4
#define MPAD 100096  // 782 * 128
#define NBUK ((NN + 255) >> 8)   // 391 buckets of 256 rows
#define B2 782                   // binning blocks
#define EPB 4096                 // edges per binning block (782*4096 >= NE)
#define NS2 (NBUK * B2)          // 305762 (bucket,block) segments
#define INV15 (1.0f / 32767.0f)

typedef _Float16 f16x8 __attribute__((ext_vector_type(8)));
typedef float f32x4 __attribute__((ext_vector_type(4)));

// ---------------------------------------------------------------- CSR build (no global atomics)

// per-block LDS bucket histogram -> exclusive h2 slice (bucket-major layout)
__global__ __launch_bounds__(256) void k_h2(const int* __restrict__ row,
                                            int* __restrict__ h2) {
    __shared__ int cnt[NBUK];
    const int b = blockIdx.x;
    for (int i = threadIdx.x; i < NBUK; i += 256) cnt[i] = 0;
    __syncthreads();
    const int e0 = b * EPB;
    const int e1 = min(e0 + EPB, NE);
    for (int e = e0 + (int)threadIdx.x; e < e1; e += 256)
        atomicAdd(&cnt[row[e] >> 8], 1);
    __syncthreads();
    for (int i = threadIdx.x; i < NBUK; i += 256) h2[i * B2 + b] = cnt[i];
}

// generic scan: blocks of 1024 (256 thr x 4 items)
__global__ __launch_bounds__(256) void k_scan1g(const int* __restrict__ in,
                                                int* __restrict__ out,
                                                int* __restrict__ bsum, int n) {
    __shared__ int s[256];
    const int t = threadIdx.x;
    const int base = blockIdx.x * 1024 + t * 4;
    int v[4];
    int sum = 0;
#pragma unroll
    for (int i = 0; i < 4; ++i) {
        v[i] = (base + i < n) ? in[base + i] : 0;
        sum += v[i];
    }
    s[t] = sum;
    __syncthreads();
    for (int off = 1; off < 256; off <<= 1) {
        int x = (t >= off) ? s[t - off] : 0;
        __syncthreads();
        s[t] += x;
        __syncthreads();
    }
    int run = (t > 0) ? s[t - 1] : 0;
#pragma unroll
    for (int i = 0; i < 4; ++i) {
        if (base + i < n) out[base + i] = run;
        run += v[i];
    }
    if (t == 255) bsum[blockIdx.x] = s[255];
}

__global__ void k_scan2(int* __restrict__ bsum, int nb) {
    if (threadIdx.x == 0 && blockIdx.x == 0) {
        int run = 0;
        for (int i = 0; i < nb; ++i) {
            int c = bsum[i];
            bsum[i] = run;
            run += c;
        }
    }
}

__global__ __launch_bounds__(256) void k_scan3g(int* __restrict__ out,
                                                const int* __restrict__ bsum,
                                                int n, int total) {
    int i = blockIdx.x * 256 + threadIdx.x;
    if (i < n)
        out[i] += bsum[i >> 10];
    else if (i == n)
        out[n] = total;
}

// bin edges into per-(bucket,block) sequential segments; LDS cursors only
__global__ __launch_bounds__(256) void k_bin(const int* __restrict__ row,
                                             const int* __restrict__ col,
                                             const float* __restrict__ val,
                                             const int* __restrict__ s2cur,
                                             int2* __restrict__ recs) {
    __shared__ int cur[NBUK];
    const int b = blockIdx.x;
    for (int i = threadIdx.x; i < NBUK; i += 256) cur[i] = s2cur[i * B2 + b];
    __syncthreads();
    const int e0 = b * EPB;
    const int e1 = min(e0 + EPB, NE);
    for (int e = e0 + (int)threadIdx.x; e < e1; e += 256) {
        const int r = row[e];
        const unsigned v15 = (unsigned)(val[e] * 32767.f + 0.5f);
        const unsigned packed = (v15 << 17) | (unsigned)col[e];
        const int p = atomicAdd(&cur[r >> 8], 1);
        int2 rec;
        rec.x = (int)packed;
        rec.y = r;
        recs[p] = rec;
    }
}

// one block per bucket: LDS row-hist -> LDS scan -> offs + place into 32KB window
__global__ __launch_bounds__(256) void k_place(const int2* __restrict__ recs,
                                               const int* __restrict__ s2cur,
                                               int* __restrict__ offs,
                                               unsigned* __restrict__ edges) {
    __shared__ int cnt[256];
    __shared__ int s[256];
    __shared__ int lcur[256];
    const int b = blockIdx.x;
    const int t = threadIdx.x;
    const int lo = b << 8;
    const int hi = min(lo + 256, NN);
    const int nr = hi - lo;
    const int base = s2cur[b * B2];
    const int end = s2cur[(b + 1) * B2];  // s2cur[NS2] = NE covers last bucket
    cnt[t] = 0;
    __syncthreads();
    for (int i = base + t; i < end; i += 256) atomicAdd(&cnt[recs[i].y - lo], 1);
    __syncthreads();
    s[t] = cnt[t];
    __syncthreads();
    for (int off = 1; off < 256; off <<= 1) {
        int x = (t >= off) ? s[t - off] : 0;
        __syncthreads();
        s[t] += x;
        __syncthreads();
    }
    const int excl = (t > 0) ? s[t - 1] : 0;
    if (t < nr) offs[lo + t] = base + excl;
    if (b == NBUK - 1 && t == 0) offs[NN] = NE;
    lcur[t] = base + excl;
    __syncthreads();
    for (int i = base + t; i < end; i += 256) {
        const int2 rec = recs[i];
        const int p = atomicAdd(&lcur[rec.y - lo], 1);
        edges[p] = (unsigned)rec.x;
    }
}

// ---------------------------------------------------------------- fp16 converts

__global__ __launch_bounds__(256) void k_cvtX(const float* __restrict__ in,
                                              _Float16* __restrict__ out) {
    const size_t base = ((size_t)blockIdx.x * 256 + threadIdx.x) * 8;
    if (base >= (size_t)NN * DD) return;
    f32x4 v0 = __builtin_nontemporal_load(reinterpret_cast<const f32x4*>(in + base));
    f32x4 v1 = __builtin_nontemporal_load(reinterpret_cast<const f32x4*>(in + base + 4));
    f16x8 o;
    o[0] = (_Float16)v0[0]; o[1] = (_Float16)v0[1]; o[2] = (_Float16)v0[2]; o[3] = (_Float16)v0[3];
    o[4] = (_Float16)v1[0]; o[5] = (_Float16)v1[1]; o[6] = (_Float16)v1[2]; o[7] = (_Float16)v1[3];
    *reinterpret_cast<f16x8*>(out + base) = o;
}

__global__ __launch_bounds__(256) void k_cvtW(const float* __restrict__ W1,
                                              const float* __restrict__ W2,
                                              const float* __restrict__ W3,
                                              const float* __restrict__ W4,
                                              _Float16* __restrict__ Wt) {
    __shared__ float s[32][33];
    const float* W = (blockIdx.z == 0) ? W1 : (blockIdx.z == 1) ? W2 : (blockIdx.z == 2) ? W3 : W4;
    _Float16* o = Wt + (size_t)blockIdx.z * DD * DD;
    const int bk = blockIdx.x * 32;
    const int bn = blockIdx.y * 32;
    const int tx = threadIdx.x & 31, ty = threadIdx.x >> 5;
    for (int r = ty; r < 32; r += 8) s[r][tx] = W[(size_t)(bk + r) * DD + bn + tx];
    __syncthreads();
    for (int r = ty; r < 32; r += 8) o[(size_t)(bn + r) * DD + bk + tx] = (_Float16)s[tx][r];
}

// ---------------------------------------------------------------- GEMM fp16 MFMA

__device__ __forceinline__ void load_lds16(const void* g, void* l) {
    __builtin_amdgcn_global_load_lds((const __attribute__((address_space(1))) void*)g,
                                     (__attribute__((address_space(3))) void*)l, 16, 0, 0);
}

__global__ __launch_bounds__(512, 4) void k_gemm_h(const _Float16* __restrict__ X,
                                                   const _Float16* __restrict__ Wt,
                                                   _Float16* __restrict__ Y) {
    __shared__ __align__(16) char lds[49152];  // A[2][8192] | B[2][16384]
    char* const Albase = lds;
    char* const Blbase = lds + 16384;

    const int tid = threadIdx.x;
    const int lane = tid & 63;
    const int wid = tid >> 6;
    const int wr = wid >> 2;
    const int wc = wid & 3;
    const int bm = blockIdx.x * 128;

    const int aoffl = wid * 1024 + lane * 16;
    const int arw = aoffl >> 6;
    const int acb = (aoffl & 63) ^ (((arw >> 1) & 3) << 4);
    const char* const Asrc0 = (const char*)X + ((size_t)(bm + arw) * DD) * 2 + acb;
    char* const Adst0 = Albase + wid * 1024;

    const int boffl0 = wid * 1024 + lane * 16;
    const int brw0 = boffl0 >> 6;
    const int bcb0 = (boffl0 & 63) ^ (((brw0 >> 1) & 3) << 4);
    const char* const Bsrc0 = (const char*)Wt + ((size_t)brw0 * DD) * 2 + bcb0;
    const int boffl1 = 8192 + wid * 1024 + lane * 16;
    const int brw1 = boffl1 >> 6;
    const int bcb1 = (boffl1 & 63) ^ (((brw1 >> 1) & 3) << 4);
    const char* const Bsrc1 = (const char*)Wt + ((size_t)brw1 * DD) * 2 + bcb1;
    char* const Bdst0 = Blbase + wid * 1024;
    char* const Bdst1 = Blbase + 8192 + wid * 1024;

    int aro[4], bro[4];
#pragma unroll
    for (int m = 0; m < 4; ++m) {
        const int r = wr * 64 + m * 16 + (lane & 15);
        aro[m] = r * 64 + ((((lane >> 4) * 16)) ^ (((r >> 1) & 3) << 4));
    }
#pragma unroll
    for (int n = 0; n < 4; ++n) {
        const int r = wc * 64 + n * 16 + (lane & 15);
        bro[n] = r * 64 + ((((lane >> 4) * 16)) ^ (((r >> 1) & 3) << 4));
    }

    f32x4 acc[4][4];
#pragma unroll
    for (int m = 0; m < 4; ++m)
#pragma unroll
        for (int n = 0; n < 4; ++n) acc[m][n] = (f32x4){0.f, 0.f, 0.f, 0.f};

    load_lds16(Asrc0, Adst0);
    load_lds16(Bsrc0, Bdst0);
    load_lds16(Bsrc1, Bdst1);
    __syncthreads();

    for (int kt = 0; kt < 8; ++kt) {
        const int cur = kt & 1;
        if (kt < 7) {
            const size_t kb = (size_t)(kt + 1) * 32 * 2;
            load_lds16(Asrc0 + kb, Adst0 + (cur ^ 1) * 8192);
            load_lds16(Bsrc0 + kb, Bdst0 + (cur ^ 1) * 16384);
            load_lds16(Bsrc1 + kb, Bdst1 + (cur ^ 1) * 16384);
        }
        const char* Ab = Albase + cur * 8192;
        const char* Bb = Blbase + cur * 16384;
        f16x8 af[4], bf[4];
#pragma unroll
        for (int m = 0; m < 4; ++m) af[m] = *reinterpret_cast<const f16x8*>(Ab + aro[m]);
#pragma unroll
        for (int n = 0; n < 4; ++n) bf[n] = *reinterpret_cast<const f16x8*>(Bb + bro[n]);
#pragma unroll
        for (int m = 0; m < 4; ++m)
#pragma unroll
            for (int n = 0; n < 4; ++n)
                acc[m][n] = __builtin_amdgcn_mfma_f32_16x16x32_f16(af[m], bf[n], acc[m][n], 0, 0, 0);
        __syncthreads();
    }

#pragma unroll
    for (int m = 0; m < 4; ++m) {
        const int row = bm + wr * 64 + m * 16 + (lane >> 4) * 4;
#pragma unroll
        for (int n = 0; n < 4; ++n) {
            const int col = wc * 64 + n * 16 + (lane & 15);
#pragma unroll
            for (int j = 0; j < 4; ++j)
                Y[(size_t)(row + j) * DD + col] = (_Float16)acc[m][n][j];
        }
    }
}

// ---------------------------------------------------------------- SpMM fp16 (full D)

__global__ __launch_bounds__(256) void k_spmm_h(const int* __restrict__ offs,
                                                const unsigned* __restrict__ edges,
                                                const _Float16* __restrict__ Y,
                                                const float* __restrict__ blend,
                                                _Float16* __restrict__ Xout) {
    const int row = blockIdx.x * 4 + (threadIdx.x >> 6);
    if (row >= NN) return;
    const int lane = threadIdx.x & 63;
    const int half = lane >> 5;
    const int sub = lane & 31;
    const int e0 = offs[row], e1 = offs[row + 1];
    float acc[8] = {};
    int e = e0 + half;
    for (; e + 6 < e1; e += 8) {
        const unsigned u0 = edges[e], u1 = edges[e + 2], u2 = edges[e + 4], u3 = edges[e + 6];
        const float v0 = (float)(u0 >> 17) * INV15;
        const float v1 = (float)(u1 >> 17) * INV15;
        const float v2 = (float)(u2 >> 17) * INV15;
        const float v3 = (float)(u3 >> 17) * INV15;
        const f16x8 y0 = *reinterpret_cast<const f16x8*>(Y + ((size_t)(u0 & 0x1FFFFu) << 8) + sub * 8);
        const f16x8 y1 = *reinterpret_cast<const f16x8*>(Y + ((size_t)(u1 & 0x1FFFFu) << 8) + sub * 8);
        const f16x8 y2 = *reinterpret_cast<const f16x8*>(Y + ((size_t)(u2 & 0x1FFFFu) << 8) + sub * 8);
        const f16x8 y3 = *reinterpret_cast<const f16x8*>(Y + ((size_t)(u3 & 0x1FFFFu) << 8) + sub * 8);
#pragma unroll
        for (int j = 0; j < 8; ++j)
            acc[j] += v0 * (float)y0[j] + v1 * (float)y1[j] + v2 * (float)y2[j] + v3 * (float)y3[j];
    }
    for (; e < e1; e += 2) {
        const unsigned u = edges[e];
        const float v = (float)(u >> 17) * INV15;
        const f16x8 y = *reinterpret_cast<const f16x8*>(Y + ((size_t)(u & 0x1FFFFu) << 8) + sub * 8);
#pragma unroll
        for (int j = 0; j < 8; ++j) acc[j] += v * (float)y[j];
    }
#pragma unroll
    for (int j = 0; j < 8; ++j) acc[j] += __shfl_xor(acc[j], 32);
    if (half == 0) {
        const size_t bi = (size_t)row * DD + sub * 8;
        const f32x4 t0 = __builtin_nontemporal_load(reinterpret_cast<const f32x4*>(blend + bi));
        const f32x4 t1 = __builtin_nontemporal_load(reinterpret_cast<const f32x4*>(blend + bi + 4));
        f16x8 o;
        o[0] = (_Float16)(0.5f * fmaxf(acc[0], 0.f) + 0.5f * t0[0]);
        o[1] = (_Float16)(0.5f * fmaxf(acc[1], 0.f) + 0.5f * t0[1]);
        o[2] = (_Float16)(0.5f * fmaxf(acc[2], 0.f) + 0.5f * t0[2]);
        o[3] = (_Float16)(0.5f * fmaxf(acc[3], 0.f) + 0.5f * t0[3]);
        o[4] = (_Float16)(0.5f * fmaxf(acc[4], 0.f) + 0.5f * t1[0]);
        o[5] = (_Float16)(0.5f * fmaxf(acc[5], 0.f) + 0.5f * t1[1]);
        o[6] = (_Float16)(0.5f * fmaxf(acc[6], 0.f) + 0.5f * t1[2]);
        o[7] = (_Float16)(0.5f * fmaxf(acc[7], 0.f) + 0.5f * t1[3]);
        *reinterpret_cast<f16x8*>(Xout + bi) = o;
    }
}

// Last layer: fused agg -> blend(z) -> Y5 = blended @ W5 (fp32) and q columns.
__global__ __launch_bounds__(256) void k_spmm_last(const int* __restrict__ offs,
                                                   const unsigned* __restrict__ edges,
                                                   const _Float16* __restrict__ Y,
                                                   const float* __restrict__ z,
                                                   const float* __restrict__ W5,
                                                   const float* __restrict__ cl,
                                                   float* __restrict__ Y5,
                                                   float* __restrict__ out) {
    const int row = blockIdx.x * 4 + (threadIdx.x >> 6);
    if (row >= NN) return;
    const int lane = threadIdx.x & 63;
    const int half = lane >> 5;
    const int sub = lane & 31;
    const int e0 = offs[row], e1 = offs[row + 1];
    float acc[8] = {};
    int e = e0 + half;
    for (; e + 6 < e1; e += 8) {
        const unsigned u0 = edges[e], u1 = edges[e + 2], u2 = edges[e + 4], u3 = edges[e + 6];
        const float v0 = (float)(u0 >> 17) * INV15;
        const float v1 = (float)(u1 >> 17) * INV15;
        const float v2 = (float)(u2 >> 17) * INV15;
        const float v3 = (float)(u3 >> 17) * INV15;
        const f16x8 y0 = *reinterpret_cast<const f16x8*>(Y + ((size_t)(u0 & 0x1FFFFu) << 8) + sub * 8);
        const f16x8 y1 = *reinterpret_cast<const f16x8*>(Y + ((size_t)(u1 & 0x1FFFFu) << 8) + sub * 8);
        const f16x8 y2 = *reinterpret_cast<const f16x8*>(Y + ((size_t)(u2 & 0x1FFFFu) << 8) + sub * 8);
        const f16x8 y3 = *reinterpret_cast<const f16x8*>(Y + ((size_t)(u3 & 0x1FFFFu) << 8) + sub * 8);
#pragma unroll
        for (int j = 0; j < 8; ++j)
            acc[j] += v0 * (float)y0[j] + v1 * (float)y1[j] + v2 * (float)y2[j] + v3 * (float)y3[j];
    }
    for (; e < e1; e += 2) {
        const unsigned u = edges[e];
        const float v = (float)(u >> 17) * INV15;
        const f16x8 y = *reinterpret_cast<const f16x8*>(Y + ((size_t)(u & 0x1FFFFu) << 8) + sub * 8);
#pragma unroll
        for (int j = 0; j < 8; ++j) acc[j] += v * (float)y[j];
    }
#pragma unroll
    for (int j = 0; j < 8; ++j) acc[j] += __shfl_xor(acc[j], 32);
    if (half == 0) {
        const size_t bi = (size_t)row * DD + sub * 8;
        const f32x4 z0 = __builtin_nontemporal_load(reinterpret_cast<const f32x4*>(z + bi));
        const f32x4 z1 = __builtin_nontemporal_load(reinterpret_cast<const f32x4*>(z + bi + 4));
        const float zb[8] = {z0[0], z0[1], z0[2], z0[3], z1[0], z1[1], z1[2], z1[3]};
        float p[4] = {0.f, 0.f, 0.f, 0.f};
        float zz = 0.f;
#pragma unroll
        for (int j = 0; j < 8; ++j) {
            const float b = 0.5f * fmaxf(acc[j], 0.f) + 0.5f * zb[j];
            const f32x4 w = *reinterpret_cast<const f32x4*>(W5 + (size_t)(sub * 8 + j) * KC);
            p[0] += b * w[0];
            p[1] += b * w[1];
            p[2] += b * w[2];
            p[3] += b * w[3];
            zz += zb[j] * zb[j];
        }
        float dot[4] = {0.f, 0.f, 0.f, 0.f}, cc[4] = {0.f, 0.f, 0.f, 0.f};
#pragma unroll
        for (int c2 = 0; c2 < 4; ++c2) {
            const f32x4 c40 = *reinterpret_cast<const f32x4*>(cl + (size_t)c2 * DD + sub * 8);
            const f32x4 c41 = *reinterpret_cast<const f32x4*>(cl + (size_t)c2 * DD + sub * 8 + 4);
            dot[c2] = zb[0] * c40[0] + zb[1] * c40[1] + zb[2] * c40[2] + zb[3] * c40[3] +
                      zb[4] * c41[0] + zb[5] * c41[1] + zb[6] * c41[2] + zb[7] * c41[3];
            cc[c2] = c40[0] * c40[0] + c40[1] * c40[1] + c40[2] * c40[2] + c40[3] * c40[3] +
                     c41[0] * c41[0] + c41[1] * c41[1] + c41[2] * c41[2] + c41[3] * c41[3];
        }
#pragma unroll
        for (int o = 16; o; o >>= 1) {
            zz += __shfl_xor(zz, o);
#pragma unroll
            for (int c2 = 0; c2 < 4; ++c2) {
                p[c2] += __shfl_xor(p[c2], o);
                dot[c2] += __shfl_xor(dot[c2], o);
                cc[c2] += __shfl_xor(cc[c2], o);
            }
        }
        if (sub == 0) {
            *reinterpret_cast<f32x4*>(Y5 + (size_t)row * KC) = (f32x4){p[0], p[1], p[2], p[3]};
            float q[4], s = 0.f;
#pragma unroll
            for (int c2 = 0; c2 < 4; ++c2) {
                const float d2 = zz - 2.f * dot[c2] + cc[c2];
                q[c2] = 1.f / (1.f + d2);
                s += q[c2];
            }
            const float inv = 1.f / s;
            *reinterpret_cast<f32x4*>(out + (size_t)row * 8 + 4) =
                (f32x4){q[0] * inv, q[1] * inv, q[2] * inv, q[3] * inv};
        }
    }
}

// ---------------------------------------------------------------- softmax tail

__device__ inline float wred(float v) {
#pragma unroll
    for (int o = 32; o; o >>= 1) v += __shfl_down(v, o);
    return v;
}

__global__ __launch_bounds__(256) void k_sm5(const int* __restrict__ offs,
                                             const unsigned* __restrict__ edges,
                                             const float* __restrict__ Y5,
                                             float* __restrict__ out) {
    const int row = blockIdx.x * 4 + (threadIdx.x >> 6);
    if (row >= NN) return;
    const int lane = threadIdx.x & 63;
    const int e0 = offs[row], e1 = offs[row + 1];
    float ax = 0.f, ay = 0.f, az = 0.f, aw = 0.f;
    for (int e = e0 + lane; e < e1; e += 64) {
        const unsigned u = edges[e];
        const float v = (float)(u >> 17) * INV15;
        const f32x4 y = *reinterpret_cast<const f32x4*>(Y5 + (size_t)(u & 0x1FFFFu) * KC);
        ax += v * y[0];
        ay += v * y[1];
        az += v * y[2];
        aw += v * y[3];
    }
    ax = wred(ax);
    ay = wred(ay);
    az = wred(az);
    aw = wred(aw);
    if (lane == 0) {
        float m = fmaxf(fmaxf(ax, ay), fmaxf(az, aw));
        float ex = __expf(ax - m), ey = __expf(ay - m), ez = __expf(az - m), ew = __expf(aw - m);
        float inv = 1.f / (ex + ey + ez + ew);
        *reinterpret_cast<f32x4*>(out + (size_t)row * 8) =
            (f32x4){ex * inv, ey * inv, ez * inv, ew * inv};
    }
}

// ---------------------------------------------------------------- launch

extern "C" void kernel_launch(void* const* d_in, const int* in_sizes, int n_in,
                              void* d_out, int out_size, void* d_ws, size_t ws_size,
                              hipStream_t stream) {
    const float* enc = (const float*)d_in[0];
    const float* tra1 = (const float*)d_in[1];
    const float* tra2 = (const float*)d_in[2];
    const float* tra3 = (const float*)d_in[3];
    const float* z = (const float*)d_in[4];
    const int* erow = (const int*)d_in[5];
    const int* ecol = (const int*)d_in[6];
    const float* evals = (const float*)d_in[7];
    const float* W1 = (const float*)d_in[8];
    const float* W2 = (const float*)d_in[9];
    const float* W3 = (const float*)d_in[10];
    const float* W4 = (const float*)d_in[11];
    const float* W5 = (const float*)d_in[12];
    const float* cluster = (const float*)d_in[13];
    float* out = (float*)d_out;

    char* ws = (char*)d_ws;
    size_t off = 0;
    auto take = [&](size_t bytes) -> void* {
        void* p = ws + off;
        off = (off + bytes + 255) & ~(size_t)255;
        return p;
    };
    int* offs = (int*)take((size_t)(NN + 1) * 4);
    int* h2 = (int*)take((size_t)NS2 * 4);
    int* s2cur = (int*)take((size_t)(NS2 + 1) * 4);
    int* bsum = (int*)take(4096);
    int2* recs = (int2*)take((size_t)NE * 8);
    unsigned* edges = (unsigned*)take((size_t)NE * 4);
    _Float16* Xa = (_Float16*)take((size_t)MPAD * DD * 2);
    _Float16* Xb = (_Float16*)take((size_t)MPAD * DD * 2);
    _Float16* Wt = (_Float16*)take((size_t)4 * DD * DD * 2);
    float* Y5 = (float*)take((size_t)NN * KC * 4);

    // CSR build: LDS multisplit, no global atomics, no memsets
    k_h2<<<B2, 256, 0, stream>>>(erow, h2);
    const int nb2 = (NS2 + 1023) / 1024;  // 299
    k_scan1g<<<nb2, 256, 0, stream>>>(h2, s2cur, bsum, NS2);
    k_scan2<<<1, 64, 0, stream>>>(bsum, nb2);
    k_scan3g<<<(NS2 + 256) / 256, 256, 0, stream>>>(s2cur, bsum, NS2, NE);
    k_bin<<<B2, 256, 0, stream>>>(erow, ecol, evals, s2cur, recs);
    k_place<<<NBUK, 256, 0, stream>>>(recs, s2cur, offs, edges);

    k_cvtX<<<(NN * DD / 8 + 255) / 256, 256, 0, stream>>>(enc, Xa);
    k_cvtW<<<dim3(8, 8, 4), 256, 0, stream>>>(W1, W2, W3, W4, Wt);

    const int gb = MPAD / 128;  // 782
    const int rb = NN / 4;      // 25000

    k_gemm_h<<<gb, 512, 0, stream>>>(Xa, Wt + 0 * DD * DD, Xb);
    k_spmm_h<<<rb, 256, 0, stream>>>(offs, edges, Xb, tra1, Xa);

    k_gemm_h<<<gb, 512, 0, stream>>>(Xa, Wt + 1 * DD * DD, Xb);
    k_spmm_h<<<rb, 256, 0, stream>>>(offs, edges, Xb, tra2, Xa);

    k_gemm_h<<<gb, 512, 0, stream>>>(Xa, Wt + 2 * DD * DD, Xb);
    k_spmm_h<<<rb, 256, 0, stream>>>(offs, edges, Xb, tra3, Xa);

    k_gemm_h<<<gb, 512, 0, stream>>>(Xa, Wt + 3 * DD * DD, Xb);
    k_spmm_last<<<rb, 256, 0, stream>>>(offs, edges, Xb, z, W5, cluster, Y5, out);

    k_sm5<<<rb, 256, 0, stream>>>(offs, edges, Y5, out);
}